// Round 15
// baseline (122.229 us; speedup 1.0000x reference)
//
#include <hip/hip_runtime.h>

typedef unsigned short u16;
typedef unsigned int u32;
typedef __bf16 bf16x8 __attribute__((ext_vector_type(8)));
typedef float f32x4 __attribute__((ext_vector_type(4)));

// Prepped-weight layout in g_wbuf (bytes), rewritten fully by prep_kernel
// every launch (deterministic):
//   W1f @ 0      : 7kt*10nt*64lane*8elem u16 = 71680 B  (K 200->224, N 150->160, zero-padded)
//   W2f @ 71680  : 5kt*7nt*64lane*8elem u16  = 35840 B  (K 150->160, N 100->112, zero-padded)
//   b1p @ 107520 : 160 f32 (zero-padded)
//   b2p @ 108160 : 112 f32 (zero-padded)
#define W2F_OFF 71680
#define B1_OFF 107520
#define B2_OFF 108160
#define WS_BYTES 108608

__device__ __align__(256) unsigned char g_wbuf[WS_BYTES];

__device__ __forceinline__ u16 f2bf(float f) {
  __bf16 b = (__bf16)f;                    // hw RNE convert
  return __builtin_bit_cast(u16, b);
}
__device__ __forceinline__ u32 pk2bf(float a, float b) {
  return (u32)f2bf(a) | ((u32)f2bf(b) << 16);  // fuses to v_cvt_pk_bf16_f32
}

__global__ void prep_kernel(const float* __restrict__ W1, const float* __restrict__ b1,
                            const float* __restrict__ W2, const float* __restrict__ b2)
{
  const int stride = gridDim.x * blockDim.x;
  const int tid0 = blockIdx.x * blockDim.x + threadIdx.x;
  u16* w1f = (u16*)g_wbuf;
  for (int e = tid0; e < 35840; e += stride) {
    int j = e & 7, l = (e >> 3) & 63, nt = (e >> 9) % 10, kt = e / 5120;
    int k = kt * 32 + ((l >> 4) << 3) + j;
    int n = nt * 16 + (l & 15);
    w1f[e] = (k < 200 && n < 150) ? f2bf(W1[k * 150 + n]) : (u16)0;
  }
  u16* w2f = (u16*)(g_wbuf + W2F_OFF);
  for (int e = tid0; e < 17920; e += stride) {
    int j = e & 7, l = (e >> 3) & 63, nt = (e >> 9) % 7, kt = e / 3584;
    int k = kt * 32 + ((l >> 4) << 3) + j;
    int n = nt * 16 + (l & 15);
    w2f[e] = (k < 150 && n < 100) ? f2bf(W2[k * 100 + n]) : (u16)0;
  }
  float* b1p = (float*)(g_wbuf + B1_OFF);
  for (int e = tid0; e < 160; e += stride) b1p[e] = (e < 150) ? b1[e] : 0.f;
  float* b2p = (float*)(g_wbuf + B2_OFF);
  for (int e = tid0; e < 112; e += stride) b2p[e] = (e < 100) ? b2[e] : 0.f;
}

// BM=64, 320 threads (5 waves). ZERO-DUPLICATION nt-partition: wave wv owns
// ALL 4 m-tiles x 2 n-tiles (G1: nt {2wv,2wv+1}; G2: {2,2,1,1,1}) -> every
// W fragment is read by exactly ONE wave per block: W L2 traffic halves vs
// R7 (430 vs 860 MB/kernel) and per-kt B-burst drops 5->2. acc1/acc2 = 32
// AGPR each (non-overlapping lifetimes); depth-1 B lookahead kept. Same R7
// swizzled staging (3200 chunks = 10 x 320 exactly) + 4-barrier skeleton.
// LDS 28160 B -> 3 blocks/CU at (320,4) = 15 waves (47%).
__global__ __launch_bounds__(320, 4)
void fused_mlp(const float* __restrict__ x, float* __restrict__ out, int B)
{
  __shared__ __align__(16) u16 xs[12800];   // 24576B swizzled frags + 512B compact + pad
  __shared__ float ps[2][5][64];            // [phase][wave][block row] partial sums

  const int tid = threadIdx.x;
  const int lane = tid & 63;
  const int wv = tid >> 6;                  // 0..4
  const int cl = lane & 15, gr = lane >> 4;
  const long r0 = (long)blockIdx.x * 64;

  const u16* w1g = (const u16*)g_wbuf;
  const u16* w2g = (const u16*)(g_wbuf + W2F_OFF);

  // ---- stage x tile: coalesced float4 -> packed bf16 -> swizzled LDS ----
  const float* xg = x + r0 * 200;
  #pragma unroll
  for (int i = 0; i < 10; ++i) {
    int c = tid + i * 320;                  // 64 rows * 50 chunks = 3200 = 10*320
    int row = c / 50, kc = c % 50;
    float4 v = *reinterpret_cast<const float4*>(xg + row * 200 + kc * 4);
    int k0 = kc * 4;
    int mt = row >> 4;
    int idx;
    if (k0 < 192) {
      int F = mt * 6 + (k0 >> 5);
      int fl = (row & 15) | (((k0 & 31) >> 3) << 4);
      idx = (F * 64 + (fl ^ (F & 7))) * 8 + (k0 & 7);
    } else {                                // k 192..199 -> compact region
      idx = 12288 + mt * 128 + (row & 15) * 8 + (k0 - 192);
    }
    uint2 p;
    p.x = pk2bf(v.x, v.y);
    p.y = pk2bf(v.z, v.w);
    *reinterpret_cast<uint2*>(&xs[idx]) = p;
  }

  // preload kt=0 B-frags (no xs dependency -> overlaps staging)
  bf16x8 bfr[2];
  #pragma unroll
  for (int nt = 0; nt < 2; ++nt)
    bfr[nt] = *reinterpret_cast<const bf16x8*>(w1g + ((0 * 10 + 2 * wv + nt) * 64 + lane) * 8);

  __syncthreads();   // (1) xs fully staged

  const f32x4 zz = {0.f, 0.f, 0.f, 0.f};
  f32x4 acc1[2][4];                         // [nt][mt]
  #pragma unroll
  for (int nt = 0; nt < 2; ++nt)
    #pragma unroll
    for (int mt = 0; mt < 4; ++mt) acc1[nt][mt] = zz;

  // ---- GEMM1: [64 x 224] @ [224 x 32] per wave, depth-1 B lookahead ----
  #pragma unroll
  for (int kt = 0; kt < 7; ++kt) {
    bf16x8 bnx[2];
    if (kt < 6) {
      #pragma unroll
      for (int nt = 0; nt < 2; ++nt)
        bnx[nt] = *reinterpret_cast<const bf16x8*>(w1g + (((kt + 1) * 10 + 2 * wv + nt) * 64 + lane) * 8);
    }
    bf16x8 a[4];
    if (kt < 6) {
      #pragma unroll
      for (int mt = 0; mt < 4; ++mt) {
        int F = mt * 6 + kt;
        a[mt] = *reinterpret_cast<const bf16x8*>(&xs[(F * 64 + (lane ^ (F & 7))) * 8]);
      }
    } else {                                // kt==6: k 192..223, only gr==0 real
      #pragma unroll
      for (int mt = 0; mt < 4; ++mt) {
        union { bf16x8 v; u32 w[4]; } A;
        A.v = *reinterpret_cast<const bf16x8*>(&xs[12288 + mt * 128 + cl * 8]);
        if (gr != 0) { A.w[0] = A.w[1] = A.w[2] = A.w[3] = 0u; }
        a[mt] = A.v;
      }
    }
    #pragma unroll
    for (int nt = 0; nt < 2; ++nt)
      #pragma unroll
      for (int mt = 0; mt < 4; ++mt)
        acc1[nt][mt] = __builtin_amdgcn_mfma_f32_16x16x32_bf16(a[mt], bfr[nt], acc1[nt][mt], 0, 0, 0);
    if (kt < 6) {
      bfr[0] = bnx[0]; bfr[1] = bnx[1];
    }
  }
  __syncthreads();   // (2) all GEMM1 A-reads done before h1 overwrites xs

  // ---- epilogue 1: bias + leaky, out1 partials, h1 -> xs as GEMM2 A-frags ----
  const float* b1p = (const float*)(g_wbuf + B1_OFF);
  float b1v[2];
  #pragma unroll
  for (int nt = 0; nt < 2; ++nt) b1v[nt] = b1p[(2 * wv + nt) * 16 + cl];

  float rs[4][4] = {{0,0,0,0},{0,0,0,0},{0,0,0,0},{0,0,0,0}};
  #pragma unroll
  for (int nt = 0; nt < 2; ++nt) {
    int k2 = (2 * wv + nt) * 16 + cl;       // h1 column = GEMM2 k index
    int kt2 = k2 >> 5;
    int l2base = 16 * ((k2 & 31) >> 3);
    int e2 = k2 & 7;
    #pragma unroll
    for (int mt = 0; mt < 4; ++mt) {
      #pragma unroll
      for (int j = 0; j < 4; ++j) {
        int l2 = gr * 4 + j + l2base;       // C/D: row=(lane>>4)*4+reg, col=lane&15
        float hv = acc1[nt][mt][j] + b1v[nt];
        hv = (hv >= 0.f) ? hv : 0.1f * hv;
        rs[mt][j] += hv;
        xs[((mt * 5 + kt2) * 64 + l2) * 8 + e2] = f2bf(hv);
      }
    }
  }
  #pragma unroll
  for (int mt = 0; mt < 4; ++mt)
    #pragma unroll
    for (int j = 0; j < 4; ++j) {
      float s = rs[mt][j];
      #pragma unroll
      for (int mask = 1; mask < 16; mask <<= 1) s += __shfl_xor(s, mask, 64);
      if (cl == 0) ps[0][wv][mt * 16 + gr * 4 + j] = s;
    }

  // GEMM2 ownership + kt=0 B preload issued BEFORE the barrier (w2g only,
  // no xs dependency -> L2 latency hides under the barrier)
  const int n2 = (wv < 2) ? 2 : 1;
  const int base2 = (wv < 2) ? 2 * wv : wv + 2;
  bf16x8 b2r[2];
  #pragma unroll
  for (int nt = 0; nt < 2; ++nt)
    if (nt < n2)
      b2r[nt] = *reinterpret_cast<const bf16x8*>(w2g + ((0 * 7 + base2 + nt) * 64 + lane) * 8);

  __syncthreads();   // (3) h1 frags + out1 partials visible

  if (tid < 64)
    out[r0 + tid] = (ps[0][0][tid] + ps[0][1][tid] + ps[0][2][tid] +
                     ps[0][3][tid] + ps[0][4][tid]) * (1.f / 150.f);

  // ---- GEMM2: [64 x 160] @ [160 x 32/16] per wave, depth-1 B lookahead ----
  f32x4 acc2[2][4];
  #pragma unroll
  for (int nt = 0; nt < 2; ++nt)
    #pragma unroll
    for (int mt = 0; mt < 4; ++mt) acc2[nt][mt] = zz;

  #pragma unroll
  for (int kt = 0; kt < 5; ++kt) {
    bf16x8 bnx2[2];
    if (kt < 4) {
      #pragma unroll
      for (int nt = 0; nt < 2; ++nt)
        if (nt < n2)
          bnx2[nt] = *reinterpret_cast<const bf16x8*>(w2g + (((kt + 1) * 7 + base2 + nt) * 64 + lane) * 8);
    }
    bf16x8 a[4];
    #pragma unroll
    for (int mt = 0; mt < 4; ++mt)
      a[mt] = *reinterpret_cast<const bf16x8*>(&xs[((mt * 5 + kt) * 64 + lane) * 8]);
    #pragma unroll
    for (int nt = 0; nt < 2; ++nt) {
      if (nt < n2) {
        #pragma unroll
        for (int mt = 0; mt < 4; ++mt)
          acc2[nt][mt] = __builtin_amdgcn_mfma_f32_16x16x32_bf16(a[mt], b2r[nt], acc2[nt][mt], 0, 0, 0);
      }
    }
    if (kt < 4) {
      #pragma unroll
      for (int nt = 0; nt < 2; ++nt)
        if (nt < n2) b2r[nt] = bnx2[nt];
    }
  }

  // ---- epilogue 2: bias + leaky, out2 partials ----
  const float* b2p = (const float*)(g_wbuf + B2_OFF);
  float b2v[2];
  #pragma unroll
  for (int nt = 0; nt < 2; ++nt)
    b2v[nt] = (nt < n2) ? b2p[(base2 + nt) * 16 + cl] : 0.f;

  float ts[4][4] = {{0,0,0,0},{0,0,0,0},{0,0,0,0},{0,0,0,0}};
  #pragma unroll
  for (int nt = 0; nt < 2; ++nt) {
    if (nt < n2) {
      #pragma unroll
      for (int mt = 0; mt < 4; ++mt) {
        #pragma unroll
        for (int j = 0; j < 4; ++j) {
          float hv = acc2[nt][mt][j] + b2v[nt];
          hv = (hv >= 0.f) ? hv : 0.1f * hv;
          ts[mt][j] += hv;
        }
      }
    }
  }
  #pragma unroll
  for (int mt = 0; mt < 4; ++mt)
    #pragma unroll
    for (int j = 0; j < 4; ++j) {
      float s = ts[mt][j];
      #pragma unroll
      for (int mask = 1; mask < 16; mask <<= 1) s += __shfl_xor(s, mask, 64);
      if (cl == 0) ps[1][wv][mt * 16 + gr * 4 + j] = s;
    }
  __syncthreads();   // (4) out2 partials visible

  if (tid < 64)
    out[B + r0 + tid] = (ps[1][0][tid] + ps[1][1][tid] + ps[1][2][tid] +
                         ps[1][3][tid] + ps[1][4][tid]) * (1.f / 100.f);
}

extern "C" void kernel_launch(void* const* d_in, const int* in_sizes, int n_in,
                              void* d_out, int out_size, void* d_ws, size_t ws_size,
                              hipStream_t stream)
{
  const float* x  = (const float*)d_in[0];
  const float* W1 = (const float*)d_in[1];
  const float* b1 = (const float*)d_in[2];
  const float* W2 = (const float*)d_in[3];
  const float* b2 = (const float*)d_in[4];
  float* out = (float*)d_out;
  const int B = in_sizes[0] / 200;   // 262144

  prep_kernel<<<64, 256, 0, stream>>>(W1, b1, W2, b2);
  fused_mlp<<<B / 64, 320, 0, stream>>>(x, out, B);
}